// Round 5
// baseline (237.519 us; speedup 1.0000x reference)
//
#include <hip/hip_runtime.h>

// MVC log-domain 3D conv — single fused kernel (re-fusion of the split pipeline
// into the round-2..4 conv structure; no logx scratch, 16 KB workspace only).
//
//   out[b,co,z,y,x] = exp2(min(126, sum_{ci,tap} w[co,tap,ci]*log2x[..]
//                                  + (1-wsum[co])*log2M))
//
// Structure (per block: TY=2 output rows, full-x 96, ZC=12 planes):
//   - 4-slice rolling z buffer in LDS (4 x 4rows x 98cols x 16ci bf16 = 49 KB)
//     -> 3 blocks/CU, 12 waves/CU.  Grid 768 = 2b x 8zch x 48yt = exactly 3/CU.
//   - ONE raw barrier per plane, lgkmcnt(0) only: epilogue stores free-run,
//     staging loads are compiler-counted (used only at convert time).
//   - T14 async-STAGE split: 12 float2 loads issued at iter top; log2+pack+
//     ds_write after the MFMA phase (HBM latency hidden under 45 MFMA + LDS reads;
//     convert VALU runs concurrently with other waves' MFMA).
//   - logM folded in as a 15th MFMA (A = 1/16 on the dx=1 k-slots of the
//     center-tap fragment) -> mean_ci log2x(center) in fp32.
//   - OOB (y/z halo) handled by staging: loads select 1.0f -> log2 -> 0 pad,
//     matching the reference conv's zero-padded log-domain input.
//   - x pad cols (0,97) zeroed once in prologue; staging never touches them.

#define VOX  884736            // 96^3
#define SLX  98                // 1 + 96 + 1 pad cols
#define ROWS (SLX * 16)        // 1568 shorts per LDS row
#define SROWS 4                // rows per slice (TY + 2 halo)
#define SSs  (SROWS * ROWS)    // 6272 shorts per slice
#define SSb  (SSs * 2)         // 12544 bytes per slice
#define NSL  4
#define TY   2
#define ZC   12

typedef __attribute__((ext_vector_type(8))) short short8;
typedef __attribute__((ext_vector_type(4))) float f32x4;

__device__ __forceinline__ unsigned short f2bf_rne(float f) {
    unsigned u = __float_as_uint(f);
    u += 0x7fff + ((u >> 16) & 1);
    return (unsigned short)(u >> 16);
}

// ---------------------------------------------------------------------------
// Weight reorg: w3[cout][k=448] MFMA A-order, wadj = 1 - sum(w).
// ---------------------------------------------------------------------------
__global__ void mvc_reorg(const float* __restrict__ w,
                          short* __restrict__ w3,
                          float* __restrict__ wadj) {
    int i = blockIdx.x * 256 + threadIdx.x;
    if (i < 16 * 448) {
        int n = i / 448, k = i % 448;
        int p = k >> 5, q = (k >> 3) & 3, j = k & 7;
        int qhi = q >> 1, ci = (q & 1) * 8 + j;
        int tap;
        bool valid = true;
        if (p < 9)        tap = (p / 3) * 9 + (p % 3) * 3 + qhi;
        else if (p < 12)  tap = (p - 9) * 9 + qhi * 3 + 2;
        else if (p == 12) tap = qhi * 9 + 8;
        else { tap = 26; valid = (qhi == 0); }
        float v = valid ? w[n * 432 + tap * 16 + ci] : 0.0f;
        w3[i] = (short)f2bf_rne(v);
    }
    if (i < 16) {
        const float* pw = w + i * 432;
        float s = 0.0f;
        for (int t = 0; t < 432; ++t) s += pw[t];
        wadj[i] = 1.0f - s;
    }
}

// ---------------------------------------------------------------------------
// Fused conv kernel.  LDS 50176 B -> 3 blocks/CU.
// ---------------------------------------------------------------------------
__global__ void __launch_bounds__(256, 3)
mvc_fused(const float* __restrict__ x,
          const short* __restrict__ w3,
          const float* __restrict__ wadj,
          float* __restrict__ out) {
    __shared__ __align__(16) short tile[NSL * SSs];   // 50176 B

    const int tid  = threadIdx.x;
    const int lane = tid & 63;
    const int wv   = tid >> 6;
    const int mn   = lane & 15;
    const int q    = lane >> 4;
    const int qlo  = q & 1;
    const int qhi  = q >> 1;

    // XCD swizzle: 6 consecutive y-tiles per XCD (y-halo L2 capture). 768 = 8*96.
    int id  = blockIdx.x;
    int xcd = id & 7, g = id >> 3;
    int yt  = xcd * 6 + g % 6;            // 0..47
    int rr  = g / 6;
    int zch = rr % 8, b = rr / 8;
    const int y0 = yt * TY;
    const int z0 = zch * ZC;

    const float* xb = x + (size_t)b * 16 * VOX;
    float* ob = out + (size_t)b * 16 * VOX;

    // loop-invariant: weight A-fragments + wadj + the logM "ones" fragment
    short8 bfr[14];
    #pragma unroll
    for (int p = 0; p < 14; ++p)
        bfr[p] = *(const short8*)(w3 + mn * 448 + p * 32 + q * 8);
    const float4 wv4 = *(const float4*)(wadj + 4 * q);
    const float wa[4] = {wv4.x, wv4.y, wv4.z, wv4.w};
    const short oc = qhi ? (short)0x3D80 : (short)0;    // 1/16 bf16 on dx=1 k-slots
    const short8 aones = {oc, oc, oc, oc, oc, oc, oc, oc};

    // ---- staging: 768 slots = 3/thread; slot = (y row, x pair, ci quad) ----
    // load_plane: issue 12 float2 loads into regs (OOB -> 1.0f => log2 -> 0 pad).
    // write_plane: log2 + bf16 pack + ds_write b64 pairs into slice (zp & 3).
    float2 h[3][4];
    auto load_plane = [&](int zp) {
        bool zin = (unsigned)zp < 96u;
        #pragma unroll
        for (int it = 0; it < 3; ++it) {
            int slot = tid + it * 256;
            int cq = slot & 3;
            int t  = slot >> 2;           // 0..191
            int xp = t % 48;
            int y  = t / 48;              // 0..3
            int gy = y0 + y - 1;
            bool inb = zin && ((unsigned)gy < 96u);
            const float* p0 = xb + (size_t)(4 * cq) * VOX
                            + ((zp * 96 + gy) * 96 + 2 * xp);
            h[it][0] = inb ? *(const float2*)(p0)            : make_float2(1.f, 1.f);
            h[it][1] = inb ? *(const float2*)(p0 + VOX)      : make_float2(1.f, 1.f);
            h[it][2] = inb ? *(const float2*)(p0 + 2 * VOX)  : make_float2(1.f, 1.f);
            h[it][3] = inb ? *(const float2*)(p0 + 3 * VOX)  : make_float2(1.f, 1.f);
        }
    };
    auto write_plane = [&](int zp) {
        short* sb = tile + ((zp + 4) & 3) * SSs;
        #pragma unroll
        for (int it = 0; it < 3; ++it) {
            int slot = tid + it * 256;
            int cq = slot & 3;
            int t  = slot >> 2;
            int xp = t % 48;
            int y  = t / 48;
            unsigned a0 = f2bf_rne(__log2f(h[it][0].x)), a1 = f2bf_rne(__log2f(h[it][1].x));
            unsigned a2 = f2bf_rne(__log2f(h[it][2].x)), a3 = f2bf_rne(__log2f(h[it][3].x));
            unsigned c0 = f2bf_rne(__log2f(h[it][0].y)), c1 = f2bf_rne(__log2f(h[it][1].y));
            unsigned c2 = f2bf_rne(__log2f(h[it][2].y)), c3 = f2bf_rne(__log2f(h[it][3].y));
            unsigned* dst = (unsigned*)(sb + (y * SLX + 1 + 2 * xp) * 16 + 4 * cq);
            *(uint2*)(dst)     = make_uint2(a0 | (a1 << 16), a2 | (a3 << 16));  // x=2xp
            *(uint2*)(dst + 8) = make_uint2(c0 | (c1 << 16), c2 | (c3 << 16));  // x=2xp+1
        }
    };

    // ---- prologue: zero pad cols (0,97) of all 4 slices; stage 3 planes ----
    if (tid < 64) {
        int rec = tid >> 1, half = tid & 1;
        int s = rec >> 3, rest = rec & 7;
        int row = rest >> 1, side = rest & 1;
        *(f32x4*)((char*)tile + s * SSb + (row * SLX + side * 97) * 32 + half * 16)
            = (f32x4){0.f, 0.f, 0.f, 0.f};
    }
    load_plane(z0 - 1); write_plane(z0 - 1);
    load_plane(z0);     write_plane(z0);
    load_plane(z0 + 1); write_plane(z0 + 1);
    __syncthreads();

    const int r  = wv >> 1;               // wave's output y row (0/1)
    const int xh = wv & 1;                // wave's x half
    const int Lb = mn * 16 + qlo * 8 + r * ROWS + qhi * 16;

    // ---- rolling z-march: one barrier per plane ----
    #pragma unroll 1
    for (int zi = 0; zi < ZC; ++zi) {
        const int z = z0 + zi;
        const bool st = (zi < ZC - 1);
        if (st) load_plane(z + 2);        // issue loads; consumed after MFMA phase
        __builtin_amdgcn_sched_barrier(0);

        const int B0 = ((z + 3) & 3) * SSs;   // plane z-1
        const int B1 = (z & 3) * SSs;         // plane z
        const int B2 = ((z + 1) & 3) * SSs;   // plane z+1

        #pragma unroll
        for (int jj = 0; jj < 3; ++jj) {
            const int j = xh * 3 + jj;
            const short* vA0 = tile + (Lb + j * 256 + B0);
            const short* vA1 = tile + (Lb + j * 256 + B1);
            const short* vA2 = tile + (Lb + j * 256 + B2);
            const short* vB0 = vA0 + 32 + qhi * 1552;      // dx=2, dy=qhi fold
            const short* vB1 = vA1 + 32 + qhi * 1552;
            const short* vB2 = vA2 + 32 + qhi * 1552;
            const short* vD  = vB2 + (3136 - qhi * 1584);  // dz2,dy2,dx2 (both halves)
            const short* vC  = vD - B2 + (qhi ? B1 : B0);  // dz=qhi, dy2, dx2

            short8 cf = *(const short8*)(vA1 + 1568);      // center fragment (reused)

            f32x4 acc = {0.f, 0.f, 0.f, 0.f};
            acc = __builtin_amdgcn_mfma_f32_16x16x32_bf16(bfr[0],  *(const short8*)(vA0),        acc, 0, 0, 0);
            acc = __builtin_amdgcn_mfma_f32_16x16x32_bf16(bfr[1],  *(const short8*)(vA0 + 1568), acc, 0, 0, 0);
            acc = __builtin_amdgcn_mfma_f32_16x16x32_bf16(bfr[2],  *(const short8*)(vA0 + 3136), acc, 0, 0, 0);
            acc = __builtin_amdgcn_mfma_f32_16x16x32_bf16(bfr[3],  *(const short8*)(vA1),        acc, 0, 0, 0);
            acc = __builtin_amdgcn_mfma_f32_16x16x32_bf16(bfr[4],  cf,                           acc, 0, 0, 0);
            acc = __builtin_amdgcn_mfma_f32_16x16x32_bf16(bfr[5],  *(const short8*)(vA1 + 3136), acc, 0, 0, 0);
            acc = __builtin_amdgcn_mfma_f32_16x16x32_bf16(bfr[6],  *(const short8*)(vA2),        acc, 0, 0, 0);
            acc = __builtin_amdgcn_mfma_f32_16x16x32_bf16(bfr[7],  *(const short8*)(vA2 + 1568), acc, 0, 0, 0);
            acc = __builtin_amdgcn_mfma_f32_16x16x32_bf16(bfr[8],  *(const short8*)(vA2 + 3136), acc, 0, 0, 0);
            acc = __builtin_amdgcn_mfma_f32_16x16x32_bf16(bfr[9],  *(const short8*)(vB0),        acc, 0, 0, 0);
            acc = __builtin_amdgcn_mfma_f32_16x16x32_bf16(bfr[10], *(const short8*)(vB1),        acc, 0, 0, 0);
            acc = __builtin_amdgcn_mfma_f32_16x16x32_bf16(bfr[11], *(const short8*)(vB2),        acc, 0, 0, 0);
            acc = __builtin_amdgcn_mfma_f32_16x16x32_bf16(bfr[12], *(const short8*)(vC),         acc, 0, 0, 0);
            acc = __builtin_amdgcn_mfma_f32_16x16x32_bf16(bfr[13], *(const short8*)(vD),         acc, 0, 0, 0);

            // logM via MFMA: mean_ci log2x of center tap
            f32x4 am = __builtin_amdgcn_mfma_f32_16x16x32_bf16(
                aones, cf, (f32x4){0.f, 0.f, 0.f, 0.f}, 0, 0, 0);
            const float lm = am[0];

            // epilogue: D row m = 4q+t = cout, col n = mn = x -> 64 B-run stores
            float* op = ob + (size_t)(4 * q) * VOX
                      + (((size_t)z * 96 + (y0 + r)) * 96 + j * 16 + mn);
            #pragma unroll
            for (int t = 0; t < 4; ++t) {
                float e = fminf(fmaf(wa[t], lm, acc[t]), 126.0f);
                op[(size_t)t * VOX] = __builtin_amdgcn_exp2f(e);
            }
        }

        if (st) {
            write_plane(z + 2);           // convert + ds_write (loads awaited here)
            asm volatile("s_waitcnt lgkmcnt(0)" ::: "memory");
            __builtin_amdgcn_s_barrier();
            __builtin_amdgcn_sched_barrier(0);
        }
    }
}

extern "C" void kernel_launch(void* const* d_in, const int* in_sizes, int n_in,
                              void* d_out, int out_size, void* d_ws, size_t ws_size,
                              hipStream_t stream) {
    const float* x = (const float*)d_in[0];
    const float* w = (const float*)d_in[1];
    float* out  = (float*)d_out;
    short* w3   = (short*)d_ws;                          // 16*448 bf16 = 14336 B
    float* wadj = (float*)((char*)d_ws + 14336);         // 16 floats

    hipLaunchKernelGGL(mvc_reorg, dim3(28),  dim3(256), 0, stream, w, w3, wadj);
    hipLaunchKernelGGL(mvc_fused, dim3(768), dim3(256), 0, stream, x, w3, wadj, out);
}

// Round 6
// 236.951 us; speedup vs baseline: 1.0024x; 1.0024x over previous
//
#include <hip/hip_runtime.h>

// MVC log-domain 3D conv — single fused kernel, 16 KB workspace.
//
//   out[b,co,z,y,x] = exp2(min(126, sum_{ci,tap} w[co,tap,ci]*log2x[..]
//                                  + (1-wsum[co])*log2M))
//
// Structure (per block: TY=2 output rows, full-x 96, ZC=12 planes):
//   - 4-slice rolling z buffer in LDS (4 x 4rows x 98cols x 16ci bf16 = 49 KB)
//     -> 3 blocks/CU, 12 waves/CU.  Grid 768 = 2b x 8zch x 48yt = exactly 3/CU.
//   - ONE raw barrier per plane, lgkmcnt(0) only.
//   - Cross-barrier T14 staging: raw float2s for plane z+2 are loaded during
//     iter z-1 and HELD IN REGISTERS across the barrier; at iter z they are
//     converted (log2+pack) and ds_written into slice (z+2)&3 -- a slice freed
//     at the previous barrier and read by nobody this iteration.  The convert
//     has a full iteration of load-latency cover (no vmcnt stall) and no
//     sched fences, so the compiler interleaves it under the MFMA phase.
//   - logM folded in as a 15th MFMA (A = 1/16 on the dx=1 k-slots of the
//     center-tap fragment) -> mean_ci log2x(center) in fp32.
//   - OOB (y/z halo) handled at load: guard selects 1.0f -> log2 -> 0 pad.
//   - x pad cols (0,97) zeroed once in prologue; staging never touches them.

#define VOX  884736            // 96^3
#define SLX  98                // 1 + 96 + 1 pad cols
#define ROWS (SLX * 16)        // 1568 shorts per LDS row
#define SROWS 4                // rows per slice (TY + 2 halo)
#define SSs  (SROWS * ROWS)    // 6272 shorts per slice
#define SSb  (SSs * 2)         // 12544 bytes per slice
#define NSL  4
#define TY   2
#define ZC   12

typedef __attribute__((ext_vector_type(8))) short short8;
typedef __attribute__((ext_vector_type(4))) float f32x4;

__device__ __forceinline__ unsigned short f2bf_rne(float f) {
    unsigned u = __float_as_uint(f);
    u += 0x7fff + ((u >> 16) & 1);
    return (unsigned short)(u >> 16);
}

// ---------------------------------------------------------------------------
// Weight reorg: w3[cout][k=448] MFMA A-order, wadj = 1 - sum(w).
// ---------------------------------------------------------------------------
__global__ void mvc_reorg(const float* __restrict__ w,
                          short* __restrict__ w3,
                          float* __restrict__ wadj) {
    int i = blockIdx.x * 256 + threadIdx.x;
    if (i < 16 * 448) {
        int n = i / 448, k = i % 448;
        int p = k >> 5, q = (k >> 3) & 3, j = k & 7;
        int qhi = q >> 1, ci = (q & 1) * 8 + j;
        int tap;
        bool valid = true;
        if (p < 9)        tap = (p / 3) * 9 + (p % 3) * 3 + qhi;
        else if (p < 12)  tap = (p - 9) * 9 + qhi * 3 + 2;
        else if (p == 12) tap = qhi * 9 + 8;
        else { tap = 26; valid = (qhi == 0); }
        float v = valid ? w[n * 432 + tap * 16 + ci] : 0.0f;
        w3[i] = (short)f2bf_rne(v);
    }
    if (i < 16) {
        const float* pw = w + i * 432;
        float s = 0.0f;
        for (int t = 0; t < 432; ++t) s += pw[t];
        wadj[i] = 1.0f - s;
    }
}

// ---------------------------------------------------------------------------
// Fused conv kernel.  LDS 50176 B -> 3 blocks/CU.
// ---------------------------------------------------------------------------
__global__ void __launch_bounds__(256, 3)
mvc_fused(const float* __restrict__ x,
          const short* __restrict__ w3,
          const float* __restrict__ wadj,
          float* __restrict__ out) {
    __shared__ __align__(16) short tile[NSL * SSs];   // 50176 B

    const int tid  = threadIdx.x;
    const int lane = tid & 63;
    const int wv   = tid >> 6;
    const int mn   = lane & 15;
    const int q    = lane >> 4;
    const int qlo  = q & 1;
    const int qhi  = q >> 1;

    // XCD swizzle: 6 consecutive y-tiles per XCD (y-halo L2 capture). 768 = 8*96.
    int id  = blockIdx.x;
    int xcd = id & 7, g = id >> 3;
    int yt  = xcd * 6 + g % 6;            // 0..47
    int rr  = g / 6;
    int zch = rr % 8, b = rr / 8;
    const int y0 = yt * TY;
    const int z0 = zch * ZC;

    const float* xb = x + (size_t)b * 16 * VOX;
    float* ob = out + (size_t)b * 16 * VOX;

    // loop-invariant: weight A-fragments + wadj + the logM "ones" fragment
    short8 bfr[14];
    #pragma unroll
    for (int p = 0; p < 14; ++p)
        bfr[p] = *(const short8*)(w3 + mn * 448 + p * 32 + q * 8);
    const float4 wv4 = *(const float4*)(wadj + 4 * q);
    const float wa[4] = {wv4.x, wv4.y, wv4.z, wv4.w};
    const short oc = qhi ? (short)0x3D80 : (short)0;    // 1/16 bf16 on dx=1 k-slots
    const short8 aones = {oc, oc, oc, oc, oc, oc, oc, oc};

    // ---- staging: 768 slots = 3/thread; slot = (y row, x pair, ci quad) ----
    // load_plane: issue 12 float2 loads into regs (OOB -> 1.0f => log2 -> 0 pad).
    // write_plane: log2 + bf16 pack + ds_write b64 pairs into slice ((zp+4) & 3).
    float2 h[3][4];
    auto load_plane = [&](int zp) {
        bool zin = (unsigned)zp < 96u;
        #pragma unroll
        for (int it = 0; it < 3; ++it) {
            int slot = tid + it * 256;
            int cq = slot & 3;
            int t  = slot >> 2;           // 0..191
            int xp = t % 48;
            int y  = t / 48;              // 0..3
            int gy = y0 + y - 1;
            bool inb = zin && ((unsigned)gy < 96u);
            const float* p0 = xb + (size_t)(4 * cq) * VOX
                            + ((zp * 96 + gy) * 96 + 2 * xp);
            h[it][0] = inb ? *(const float2*)(p0)            : make_float2(1.f, 1.f);
            h[it][1] = inb ? *(const float2*)(p0 + VOX)      : make_float2(1.f, 1.f);
            h[it][2] = inb ? *(const float2*)(p0 + 2 * VOX)  : make_float2(1.f, 1.f);
            h[it][3] = inb ? *(const float2*)(p0 + 3 * VOX)  : make_float2(1.f, 1.f);
        }
    };
    auto write_plane = [&](int zp) {
        short* sb = tile + ((zp + 4) & 3) * SSs;
        #pragma unroll
        for (int it = 0; it < 3; ++it) {
            int slot = tid + it * 256;
            int cq = slot & 3;
            int t  = slot >> 2;
            int xp = t % 48;
            int y  = t / 48;
            unsigned a0 = f2bf_rne(__log2f(h[it][0].x)), a1 = f2bf_rne(__log2f(h[it][1].x));
            unsigned a2 = f2bf_rne(__log2f(h[it][2].x)), a3 = f2bf_rne(__log2f(h[it][3].x));
            unsigned c0 = f2bf_rne(__log2f(h[it][0].y)), c1 = f2bf_rne(__log2f(h[it][1].y));
            unsigned c2 = f2bf_rne(__log2f(h[it][2].y)), c3 = f2bf_rne(__log2f(h[it][3].y));
            unsigned* dst = (unsigned*)(sb + (y * SLX + 1 + 2 * xp) * 16 + 4 * cq);
            *(uint2*)(dst)     = make_uint2(a0 | (a1 << 16), a2 | (a3 << 16));  // x=2xp
            *(uint2*)(dst + 8) = make_uint2(c0 | (c1 << 16), c2 | (c3 << 16));  // x=2xp+1
        }
    };

    // ---- prologue: zero pad cols (0,97) of all 4 slices; fill 3 planes;
    //      leave plane z0+2's raw loads held in h for iter 0's convert ----
    if (tid < 64) {
        int rec = tid >> 1, half = tid & 1;
        int s = rec >> 3, rest = rec & 7;
        int row = rest >> 1, side = rest & 1;
        *(f32x4*)((char*)tile + s * SSb + (row * SLX + side * 97) * 32 + half * 16)
            = (f32x4){0.f, 0.f, 0.f, 0.f};
    }
    load_plane(z0 - 1); write_plane(z0 - 1);
    load_plane(z0);     write_plane(z0);
    load_plane(z0 + 1); write_plane(z0 + 1);
    load_plane(z0 + 2);                    // held across the first barrier
    __syncthreads();

    const int r  = wv >> 1;               // wave's output y row (0/1)
    const int xh = wv & 1;                // wave's x half
    const int Lb = mn * 16 + qlo * 8 + r * ROWS + qhi * 16;

    // ---- rolling z-march: one barrier per plane; staging converts one iter
    //      late from held registers (full-iteration latency cover) ----
    #pragma unroll 1
    for (int zi = 0; zi < ZC; ++zi) {
        const int z = z0 + zi;

        const int B0 = ((z + 3) & 3) * SSs;   // plane z-1
        const int B1 = (z & 3) * SSs;         // plane z
        const int B2 = ((z + 1) & 3) * SSs;   // plane z+1

        #pragma unroll
        for (int jj = 0; jj < 3; ++jj) {
            const int j = xh * 3 + jj;
            const short* vA0 = tile + (Lb + j * 256 + B0);
            const short* vA1 = tile + (Lb + j * 256 + B1);
            const short* vA2 = tile + (Lb + j * 256 + B2);
            const short* vB0 = vA0 + 32 + qhi * 1552;      // dx=2, dy=qhi fold
            const short* vB1 = vA1 + 32 + qhi * 1552;
            const short* vB2 = vA2 + 32 + qhi * 1552;
            const short* vD  = vB2 + (3136 - qhi * 1584);  // dz2,dy2,dx2 (both halves)
            const short* vC  = vD - B2 + (qhi ? B1 : B0);  // dz=qhi, dy2, dx2

            short8 cf = *(const short8*)(vA1 + 1568);      // center fragment (reused)

            f32x4 acc = {0.f, 0.f, 0.f, 0.f};
            acc = __builtin_amdgcn_mfma_f32_16x16x32_bf16(bfr[0],  *(const short8*)(vA0),        acc, 0, 0, 0);
            acc = __builtin_amdgcn_mfma_f32_16x16x32_bf16(bfr[1],  *(const short8*)(vA0 + 1568), acc, 0, 0, 0);
            acc = __builtin_amdgcn_mfma_f32_16x16x32_bf16(bfr[2],  *(const short8*)(vA0 + 3136), acc, 0, 0, 0);
            acc = __builtin_amdgcn_mfma_f32_16x16x32_bf16(bfr[3],  *(const short8*)(vA1),        acc, 0, 0, 0);
            acc = __builtin_amdgcn_mfma_f32_16x16x32_bf16(bfr[4],  cf,                           acc, 0, 0, 0);
            acc = __builtin_amdgcn_mfma_f32_16x16x32_bf16(bfr[5],  *(const short8*)(vA1 + 3136), acc, 0, 0, 0);
            acc = __builtin_amdgcn_mfma_f32_16x16x32_bf16(bfr[6],  *(const short8*)(vA2),        acc, 0, 0, 0);
            acc = __builtin_amdgcn_mfma_f32_16x16x32_bf16(bfr[7],  *(const short8*)(vA2 + 1568), acc, 0, 0, 0);
            acc = __builtin_amdgcn_mfma_f32_16x16x32_bf16(bfr[8],  *(const short8*)(vA2 + 3136), acc, 0, 0, 0);
            acc = __builtin_amdgcn_mfma_f32_16x16x32_bf16(bfr[9],  *(const short8*)(vB0),        acc, 0, 0, 0);
            acc = __builtin_amdgcn_mfma_f32_16x16x32_bf16(bfr[10], *(const short8*)(vB1),        acc, 0, 0, 0);
            acc = __builtin_amdgcn_mfma_f32_16x16x32_bf16(bfr[11], *(const short8*)(vB2),        acc, 0, 0, 0);
            acc = __builtin_amdgcn_mfma_f32_16x16x32_bf16(bfr[12], *(const short8*)(vC),         acc, 0, 0, 0);
            acc = __builtin_amdgcn_mfma_f32_16x16x32_bf16(bfr[13], *(const short8*)(vD),         acc, 0, 0, 0);

            // logM via MFMA: mean_ci log2x of center tap
            f32x4 am = __builtin_amdgcn_mfma_f32_16x16x32_bf16(
                aones, cf, (f32x4){0.f, 0.f, 0.f, 0.f}, 0, 0, 0);
            const float lm = am[0];

            // epilogue: D row m = 4q+t = cout, col n = mn = x -> 64 B-run stores
            float* op = ob + (size_t)(4 * q) * VOX
                      + (((size_t)z * 96 + (y0 + r)) * 96 + j * 16 + mn);
            #pragma unroll
            for (int t = 0; t < 4; ++t) {
                float e = fminf(fmaf(wa[t], lm, acc[t]), 126.0f);
                op[(size_t)t * VOX] = __builtin_amdgcn_exp2f(e);
            }
        }

        if (zi < ZC - 1) {
            // Convert plane z+2 from registers loaded an iteration ago (no vmcnt
            // stall) into slice (z+2)&3 -- freed at the previous barrier, read by
            // nobody this iteration.  Then refill h with plane z+3's raw loads
            // (consumed next iteration; zin guard covers z+3 >= 96).
            write_plane(z + 2);
            load_plane(z + 3);
            asm volatile("s_waitcnt lgkmcnt(0)" ::: "memory");
            __builtin_amdgcn_s_barrier();
            __builtin_amdgcn_sched_barrier(0);
        }
    }
}

extern "C" void kernel_launch(void* const* d_in, const int* in_sizes, int n_in,
                              void* d_out, int out_size, void* d_ws, size_t ws_size,
                              hipStream_t stream) {
    const float* x = (const float*)d_in[0];
    const float* w = (const float*)d_in[1];
    float* out  = (float*)d_out;
    short* w3   = (short*)d_ws;                          // 16*448 bf16 = 14336 B
    float* wadj = (float*)((char*)d_ws + 14336);         // 16 floats

    hipLaunchKernelGGL(mvc_reorg, dim3(28),  dim3(256), 0, stream, w, w3, wadj);
    hipLaunchKernelGGL(mvc_fused, dim3(768), dim3(256), 0, stream, x, w3, wadj, out);
}